// Round 2
// baseline (511.429 us; speedup 1.0000x reference)
//
#include <hip/hip_runtime.h>

// VQ nearest-codeword, tiered:
//  T1: fp16 single-pass MFMA GEMM (x,E pre-packed fp16), per-row top-2 fused.
//      rows with gap < TAU1 -> list1.
//  T2: fp16 3-pass (hi*hi + hi*lo + lo*hi) MFMA re-scan of list1 rows.
//      rows with gap < TAU2 -> list2.
//  T3: exact fp64 full scan of list2 rows.
// x-fp16 pack lives in d_out (row-stride 1024B == out row size; each block
// reads only its own rows and overwrites them at the very end -> race-free).

typedef float f32x4 __attribute__((ext_vector_type(4)));
typedef _Float16 f16x8 __attribute__((ext_vector_type(8)));

#define TAU1 0.15f
#define TAU2 5e-4f

__device__ __forceinline__ unsigned short f16b(float f) {
  _Float16 h = (_Float16)f;
  return __builtin_bit_cast(unsigned short, h);
}

__device__ __forceinline__ void gl16(char* lds, const char* g) {
  __builtin_amdgcn_global_load_lds(
      (const __attribute__((address_space(1))) void*)g,
      (__attribute__((address_space(3))) void*)lds, 16, 0, 0);
}

// ---- pack x: f32 [32768][256] -> fp16 rows at stride 1024 B (in d_out) ----
__global__ void pack_x(const float* __restrict__ x, char* xp) {
  int gid = blockIdx.x * 256 + threadIdx.x;   // 524288 total
  int row = gid >> 4, seg = gid & 15;
  const float4* xr = (const float4*)(x + (size_t)row * 256 + seg * 16);
  unsigned o[8];
#pragma unroll
  for (int q = 0; q < 4; ++q) {
    float4 f = xr[q];
    o[q * 2]     = (unsigned)f16b(f.x) | ((unsigned)f16b(f.y) << 16);
    o[q * 2 + 1] = (unsigned)f16b(f.z) | ((unsigned)f16b(f.w) << 16);
  }
  uint4* dst = (uint4*)(xp + (size_t)row * 1024 + seg * 32);
  dst[0] = make_uint4(o[0], o[1], o[2], o[3]);
  dst[1] = make_uint4(o[4], o[5], o[6], o[7]);
}

// ---- pack E: fp16 hi+lo planes (512 B/row each) + e2f = ||E_v||^2 ----
__global__ void pack_e(const float* __restrict__ E, char* __restrict__ ehi,
                       char* __restrict__ elo, float* __restrict__ e2f) {
  int tid = threadIdx.x;
  int vl = tid >> 4, seg = tid & 15;
  int v = blockIdx.x * 16 + vl;
  const float4* er = (const float4*)(E + (size_t)v * 256 + seg * 16);
  unsigned oh[8], ol[8];
  double s = 0.0;
#pragma unroll
  for (int q = 0; q < 4; ++q) {
    float4 f = er[q];
    float vf[4] = {f.x, f.y, f.z, f.w};
    unsigned short hb[4], lb[4];
#pragma unroll
    for (int e = 0; e < 4; ++e) {
      float fv = vf[e];
      s += (double)fv * (double)fv;
      _Float16 h = (_Float16)fv;
      hb[e] = __builtin_bit_cast(unsigned short, h);
      float r = fv - (float)h;
      lb[e] = f16b(r);
    }
    oh[q * 2]     = (unsigned)hb[0] | ((unsigned)hb[1] << 16);
    oh[q * 2 + 1] = (unsigned)hb[2] | ((unsigned)hb[3] << 16);
    ol[q * 2]     = (unsigned)lb[0] | ((unsigned)lb[1] << 16);
    ol[q * 2 + 1] = (unsigned)lb[2] | ((unsigned)lb[3] << 16);
  }
  uint4* dh = (uint4*)(ehi + (size_t)v * 512 + seg * 32);
  dh[0] = make_uint4(oh[0], oh[1], oh[2], oh[3]);
  dh[1] = make_uint4(oh[4], oh[5], oh[6], oh[7]);
  uint4* dl = (uint4*)(elo + (size_t)v * 512 + seg * 32);
  dl[0] = make_uint4(ol[0], ol[1], ol[2], ol[3]);
  dl[1] = make_uint4(ol[4], ol[5], ol[6], ol[7]);
#pragma unroll
  for (int off = 1; off < 16; off <<= 1) s += __shfl_xor(s, off);
  if (seg == 0) e2f[v] = (float)s;
}

// ---- T1 main: BM=64, chunk=256 cols, BK=32, dbuf LDS, gload_lds staging ----
__global__ __launch_bounds__(256) void vq_main(
    const char* xpack, const char* __restrict__ epack,
    const float* __restrict__ e2f, const float* __restrict__ E,
    float* out, unsigned* __restrict__ cnt1, unsigned* __restrict__ list1) {
  extern __shared__ char smem[];
  const int tid = threadIdx.x;
  const int w = tid >> 6, lane = tid & 63;
  const int l15 = lane & 15, g = lane >> 4;
  const int rowbase = blockIdx.x * 64;

  // loader geometry (linear LDS dest, inverse-swizzled global source)
  const int rA = w * 16 + (lane >> 2);
  const int swz = (((lane & 3) ^ ((lane >> 2) & 3)) << 4);
  const char* aBase = xpack + (size_t)(rowbase + rA) * 1024 + swz;
  const char* bBase = epack + (size_t)(w * 64 + (lane >> 2)) * 512 + swz;
  const int ldA = w * 1024 + lane * 16;
  const int ldB = w * 4096 + lane * 16;

  // fragment read offsets (XOR-swizzled)
  const int fsw = ((g ^ (l15 & 3)) << 4);
  int aoff[4], boff[4];
#pragma unroll
  for (int mi = 0; mi < 4; ++mi) aoff[mi] = mi * 1024 + l15 * 64 + fsw;
#pragma unroll
  for (int ni = 0; ni < 4; ++ni) boff[ni] = w * 4096 + ni * 1024 + l15 * 64 + fsw;

  f32x4 acc[4][4];
#pragma unroll
  for (int mi = 0; mi < 4; ++mi)
#pragma unroll
    for (int ni = 0; ni < 4; ++ni) acc[mi][ni] = (f32x4){0.f, 0.f, 0.f, 0.f};

  float m1[16], m2[16];
  int i1[16];
#pragma unroll
  for (int s = 0; s < 16; ++s) { m1[s] = 3.4e38f; m2[s] = 3.4e38f; i1[s] = 0; }

#define STAGE(p, coff, koff)                                                \
  do {                                                                      \
    gl16(smem + (p)*4096 + ldA, aBase + (koff));                            \
    _Pragma("unroll") for (int i_ = 0; i_ < 4; ++i_)                        \
        gl16(smem + 8192 + (p)*16384 + ldB + i_ * 1024,                     \
             bBase + i_ * 8192 + (coff) + (koff));                          \
  } while (0)

  STAGE(0, (size_t)0, 0);
  __syncthreads();

#pragma unroll 1
  for (int c = 0; c < 16; ++c) {
    const size_t coff = (size_t)c * 131072;
#pragma unroll
    for (int k = 0; k < 8; ++k) {
      const int p = k & 1;
      if (!(c == 15 && k == 7)) {
        if (k == 7) STAGE(0, coff + 131072, 0);
        else STAGE(p ^ 1, coff, (k + 1) * 64);
      }
      const char* Ar = smem + p * 4096;
      const char* Br = smem + 8192 + p * 16384;
      f16x8 a[4], b[4];
#pragma unroll
      for (int mi = 0; mi < 4; ++mi) a[mi] = *(const f16x8*)(Ar + aoff[mi]);
#pragma unroll
      for (int ni = 0; ni < 4; ++ni) b[ni] = *(const f16x8*)(Br + boff[ni]);
#pragma unroll
      for (int mi = 0; mi < 4; ++mi)
#pragma unroll
        for (int ni = 0; ni < 4; ++ni)
          acc[mi][ni] = __builtin_amdgcn_mfma_f32_16x16x32_f16(
              a[mi], b[ni], acc[mi][ni], 0, 0, 0);
      __syncthreads();
    }
    // fused epilogue: distances + top-2, reset acc
    const int cb = c * 256 + w * 64;
#pragma unroll
    for (int ni = 0; ni < 4; ++ni) {
      const int col = cb + ni * 16 + l15;
      const float ev = e2f[col];
#pragma unroll
      for (int mi = 0; mi < 4; ++mi)
#pragma unroll
        for (int rg = 0; rg < 4; ++rg) {
          float d = fmaf(-2.0f, acc[mi][ni][rg], ev);
          const int s = mi * 4 + rg;
          bool better = d < m1[s];
          m2[s] = fminf(m2[s], better ? m1[s] : d);
          m1[s] = better ? d : m1[s];
          i1[s] = better ? col : i1[s];
          acc[mi][ni][rg] = 0.0f;
        }
    }
  }
#undef STAGE

  // butterfly merge across the 16 lanes sharing each row-set
#pragma unroll
  for (int s = 0; s < 16; ++s) {
#pragma unroll
    for (int off = 1; off < 16; off <<= 1) {
      float om1 = __shfl_xor(m1[s], off);
      float om2 = __shfl_xor(m2[s], off);
      int oi = __shfl_xor(i1[s], off);
      float nm2 = fminf(fminf(m2[s], om2), fmaxf(m1[s], om1));
      bool take = om1 < m1[s];
      m1[s] = take ? om1 : m1[s];
      i1[s] = take ? oi : i1[s];
      m2[s] = nm2;
    }
  }

  float* sm1 = (float*)smem;             // [4][64]
  float* sm2 = (float*)(smem + 1024);
  int* si1 = (int*)(smem + 2048);
  unsigned* swin = (unsigned*)(smem + 3072);
  __syncthreads();
  if (l15 == 0) {
#pragma unroll
    for (int s = 0; s < 16; ++s) {
      int r = (s >> 2) * 16 + g * 4 + (s & 3);
      sm1[w * 64 + r] = m1[s];
      sm2[w * 64 + r] = m2[s];
      si1[w * 64 + r] = i1[s];
    }
  }
  __syncthreads();
  if (tid < 64) {
    int r = tid;
    float am1 = sm1[r], am2 = sm2[r];
    int ai = si1[r];
#pragma unroll
    for (int ww = 1; ww < 4; ++ww) {
      float om1 = sm1[ww * 64 + r], om2 = sm2[ww * 64 + r];
      int oi = si1[ww * 64 + r];
      float nm2 = fminf(fminf(am2, om2), fmaxf(am1, om1));
      bool take = om1 < am1;
      am1 = take ? om1 : am1;
      ai = take ? oi : ai;
      am2 = nm2;
    }
    swin[r] = (unsigned)ai;
    if (am2 - am1 < TAU1) {
      unsigned p = atomicAdd(cnt1, 1u);
      list1[p] = (unsigned)(rowbase + r);
    }
  }
  __syncthreads();
  {
    int r = tid >> 2, part = tid & 3;
    unsigned wv = swin[r];
    const float4* src = (const float4*)(E + (size_t)wv * 256 + part * 64);
    float4* dst = (float4*)(out + (size_t)(rowbase + r) * 256 + part * 64);
#pragma unroll
    for (int q = 0; q < 16; ++q) dst[q] = src[q];
  }
}

// ---- T2: fp16 3-pass re-scan of flagged rows (16 rows/block) ----
__global__ void vq_tier2(const float* __restrict__ x, const float* __restrict__ E,
                         const char* __restrict__ ehi, const char* __restrict__ elo,
                         const float* __restrict__ e2f, float* out,
                         const unsigned* __restrict__ cnt1,
                         const unsigned* __restrict__ list1,
                         unsigned* __restrict__ cnt2, unsigned* __restrict__ list2) {
  __shared__ char As[16384];  // [hi 8192][lo 8192], swizzled
  __shared__ float sm1[4][16], sm2[4][16];
  __shared__ int si1[4][16];
  __shared__ unsigned swin[16];
  unsigned n = *cnt1;
  const int tid = threadIdx.x;
  const int wid = tid >> 6, lane = tid & 63;
  const int l15 = lane & 15, g = lane >> 4;
  for (unsigned jb = blockIdx.x * 16u; jb < n; jb += gridDim.x * 16u) {
    {  // stage + split 16 rows of x
      int jr = tid >> 4, seg = tid & 15;
      unsigned j = jb + (unsigned)jr;
      unsigned row = list1[j < n ? j : (n - 1)];
      const float* xr = x + (size_t)row * 256 + seg * 16;
      int sw = (jr & 3) << 4;
#pragma unroll
      for (int h = 0; h < 2; ++h) {
        float4 f0 = *(const float4*)(xr + h * 8);
        float4 f1 = *(const float4*)(xr + h * 8 + 4);
        float vf[8] = {f0.x, f0.y, f0.z, f0.w, f1.x, f1.y, f1.z, f1.w};
        unsigned oh[4], ol[4];
#pragma unroll
        for (int q = 0; q < 4; ++q) {
          _Float16 h0 = (_Float16)vf[q * 2];
          _Float16 h1 = (_Float16)vf[q * 2 + 1];
          unsigned short l0 = f16b(vf[q * 2] - (float)h0);
          unsigned short l1 = f16b(vf[q * 2 + 1] - (float)h1);
          oh[q] = (unsigned)__builtin_bit_cast(unsigned short, h0) |
                  ((unsigned)__builtin_bit_cast(unsigned short, h1) << 16);
          ol[q] = (unsigned)l0 | ((unsigned)l1 << 16);
        }
        int o = seg * 32 + h * 16;
        int addr = jr * 512 + (o >> 6) * 64 + ((o & 63) ^ sw);
        *(uint4*)(As + addr) = make_uint4(oh[0], oh[1], oh[2], oh[3]);
        *(uint4*)(As + 8192 + addr) = make_uint4(ol[0], ol[1], ol[2], ol[3]);
      }
    }
    __syncthreads();
    float m1l[4], m2l[4];
    int i1l[4];
#pragma unroll
    for (int s = 0; s < 4; ++s) { m1l[s] = 3.4e38f; m2l[s] = 3.4e38f; i1l[s] = 0; }
#pragma unroll 1
    for (int ch = 0; ch < 16; ++ch) {
      int cb = wid * 1024 + ch * 64;
      f32x4 acc[4];
#pragma unroll
      for (int ni = 0; ni < 4; ++ni) acc[ni] = (f32x4){0.f, 0.f, 0.f, 0.f};
#pragma unroll
      for (int ks = 0; ks < 8; ++ks) {
        int aoffh = l15 * 512 + ks * 64 + ((g ^ (l15 & 3)) << 4);
        f16x8 ah = *(const f16x8*)(As + aoffh);
        f16x8 al = *(const f16x8*)(As + 8192 + aoffh);
#pragma unroll
        for (int ni = 0; ni < 4; ++ni) {
          size_t bo = (size_t)(cb + ni * 16 + l15) * 512 + ks * 64 + g * 16;
          f16x8 bh = *(const f16x8*)(ehi + bo);
          f16x8 bl = *(const f16x8*)(elo + bo);
          acc[ni] = __builtin_amdgcn_mfma_f32_16x16x32_f16(ah, bh, acc[ni], 0, 0, 0);
          acc[ni] = __builtin_amdgcn_mfma_f32_16x16x32_f16(ah, bl, acc[ni], 0, 0, 0);
          acc[ni] = __builtin_amdgcn_mfma_f32_16x16x32_f16(al, bh, acc[ni], 0, 0, 0);
        }
      }
#pragma unroll
      for (int ni = 0; ni < 4; ++ni) {
        int c = cb + ni * 16 + l15;
        float ev = e2f[c];
#pragma unroll
        for (int rg = 0; rg < 4; ++rg) {
          float d = fmaf(-2.0f, acc[ni][rg], ev);
          bool better = d < m1l[rg];
          m2l[rg] = fminf(m2l[rg], better ? m1l[rg] : d);
          m1l[rg] = better ? d : m1l[rg];
          i1l[rg] = better ? c : i1l[rg];
        }
      }
    }
#pragma unroll
    for (int s = 0; s < 4; ++s) {
#pragma unroll
      for (int off = 1; off < 16; off <<= 1) {
        float om1 = __shfl_xor(m1l[s], off);
        float om2 = __shfl_xor(m2l[s], off);
        int oi = __shfl_xor(i1l[s], off);
        float nm2 = fminf(fminf(m2l[s], om2), fmaxf(m1l[s], om1));
        bool take = om1 < m1l[s];
        m1l[s] = take ? om1 : m1l[s];
        i1l[s] = take ? oi : i1l[s];
        m2l[s] = nm2;
      }
    }
    if (l15 == 0) {
#pragma unroll
      for (int s = 0; s < 4; ++s) {
        int r = g * 4 + s;
        sm1[wid][r] = m1l[s];
        sm2[wid][r] = m2l[s];
        si1[wid][r] = i1l[s];
      }
    }
    __syncthreads();
    if (tid < 16) {
      int r = tid;
      float am1 = sm1[0][r], am2 = sm2[0][r];
      int ai = si1[0][r];
#pragma unroll
      for (int ww = 1; ww < 4; ++ww) {
        float om1 = sm1[ww][r], om2 = sm2[ww][r];
        int oi = si1[ww][r];
        float nm2 = fminf(fminf(am2, om2), fmaxf(am1, om1));
        bool take = om1 < am1;
        am1 = take ? om1 : am1;
        ai = take ? oi : ai;
        am2 = nm2;
      }
      unsigned j = jb + (unsigned)r;
      swin[r] = (unsigned)ai;
      if (j < n && (am2 - am1 < TAU2)) {
        unsigned p = atomicAdd(cnt2, 1u);
        list2[p] = list1[j];
      }
    }
    __syncthreads();
    {
      int jr = tid >> 4, seg = tid & 15;
      unsigned j = jb + (unsigned)jr;
      if (j < n) {
        unsigned row = list1[j], wv = swin[jr];
        const float4* src = (const float4*)(E + (size_t)wv * 256 + seg * 16);
        float4* dst = (float4*)(out + (size_t)row * 256 + seg * 16);
#pragma unroll
        for (int q = 0; q < 4; ++q) dst[q] = src[q];
      }
    }
    __syncthreads();
  }
}

// ---- T3: exact fp64 direct-distance scan ----
__global__ void vq_tier3(const float* __restrict__ x, const float* __restrict__ E,
                         float* out, const unsigned* __restrict__ cnt2,
                         const unsigned* __restrict__ list2) {
  __shared__ double sd[256];
  __shared__ int si[256];
  unsigned n = *cnt2;
  for (unsigned i = blockIdx.x; i < n; i += gridDim.x) {
    unsigned row = list2[i];
    const float* xr = x + (size_t)row * 256;
    double best = 1e300;
    int bi = 1 << 30;
    for (int v = threadIdx.x; v < 4096; v += 256) {
      const float* ev = E + (size_t)v * 256;
      double a0 = 0, a1 = 0, a2 = 0, a3 = 0;
      for (int k = 0; k < 256; k += 4) {
        double d0 = (double)xr[k] - (double)ev[k];
        double d1 = (double)xr[k + 1] - (double)ev[k + 1];
        double d2 = (double)xr[k + 2] - (double)ev[k + 2];
        double d3 = (double)xr[k + 3] - (double)ev[k + 3];
        a0 += d0 * d0; a1 += d1 * d1; a2 += d2 * d2; a3 += d3 * d3;
      }
      double d = (a0 + a1) + (a2 + a3);
      if (d < best || (d == best && v < bi)) { best = d; bi = v; }
    }
    sd[threadIdx.x] = best; si[threadIdx.x] = bi;
    __syncthreads();
    for (int s = 128; s > 0; s >>= 1) {
      if ((int)threadIdx.x < s) {
        double ob = sd[threadIdx.x + s];
        int oi = si[threadIdx.x + s];
        if (ob < sd[threadIdx.x] || (ob == sd[threadIdx.x] && oi < si[threadIdx.x])) {
          sd[threadIdx.x] = ob; si[threadIdx.x] = oi;
        }
      }
      __syncthreads();
    }
    int win = si[0];
    __syncthreads();
    out[(size_t)row * 256 + threadIdx.x] = E[(size_t)win * 256 + threadIdx.x];
  }
}

// ---- insurance: exact fp64 scan of ALL rows (only if ws too small) ----
__global__ void scan_all(const float* __restrict__ x, const float* __restrict__ E,
                         float* out) {
  __shared__ double sd[256];
  __shared__ int si[256];
  for (int row = blockIdx.x; row < 32768; row += gridDim.x) {
    const float* xr = x + (size_t)row * 256;
    double best = 1e300;
    int bi = 1 << 30;
    for (int v = threadIdx.x; v < 4096; v += 256) {
      const float* ev = E + (size_t)v * 256;
      double a0 = 0, a1 = 0, a2 = 0, a3 = 0;
      for (int k = 0; k < 256; k += 4) {
        double d0 = (double)xr[k] - (double)ev[k];
        double d1 = (double)xr[k + 1] - (double)ev[k + 1];
        double d2 = (double)xr[k + 2] - (double)ev[k + 2];
        double d3 = (double)xr[k + 3] - (double)ev[k + 3];
        a0 += d0 * d0; a1 += d1 * d1; a2 += d2 * d2; a3 += d3 * d3;
      }
      double d = (a0 + a1) + (a2 + a3);
      if (d < best || (d == best && v < bi)) { best = d; bi = v; }
    }
    sd[threadIdx.x] = best; si[threadIdx.x] = bi;
    __syncthreads();
    for (int s = 128; s > 0; s >>= 1) {
      if ((int)threadIdx.x < s) {
        double ob = sd[threadIdx.x + s];
        int oi = si[threadIdx.x + s];
        if (ob < sd[threadIdx.x] || (ob == sd[threadIdx.x] && oi < si[threadIdx.x])) {
          sd[threadIdx.x] = ob; si[threadIdx.x] = oi;
        }
      }
      __syncthreads();
    }
    int win = si[0];
    __syncthreads();
    out[(size_t)row * 256 + threadIdx.x] = E[(size_t)win * 256 + threadIdx.x];
  }
}

extern "C" void kernel_launch(void* const* d_in, const int* in_sizes, int n_in,
                              void* d_out, int out_size, void* d_ws, size_t ws_size,
                              hipStream_t stream) {
  (void)in_sizes; (void)n_in; (void)out_size;
  const float* x = (const float*)d_in[0];
  const float* E = (const float*)d_in[1];
  float* out = (float*)d_out;
  char* ws = (char*)d_ws;
  const size_t NEED = 64 + 16384 + 2 * 2097152 + 2 * 131072;  // 4472896
  if (ws_size < NEED) {
    scan_all<<<2048, 256, 0, stream>>>(x, E, out);
    return;
  }
  unsigned* cnt1 = (unsigned*)ws;
  unsigned* cnt2 = (unsigned*)(ws + 4);
  float* e2f = (float*)(ws + 64);
  char* ehi = ws + 16448;
  char* elo = ehi + 2097152;
  unsigned* list1 = (unsigned*)(elo + 2097152);
  unsigned* list2 = (unsigned*)((char*)list1 + 131072);

  hipMemsetAsync(ws, 0, 64, stream);
  pack_x<<<2048, 256, 0, stream>>>(x, (char*)d_out);
  pack_e<<<256, 256, 0, stream>>>(E, ehi, elo, e2f);
  vq_main<<<512, 256, 40960, stream>>>((const char*)d_out, ehi, e2f, E, out,
                                       cnt1, list1);
  vq_tier2<<<64, 256, 0, stream>>>(x, E, ehi, elo, e2f, out, cnt1, list1,
                                   cnt2, list2);
  vq_tier3<<<128, 256, 0, stream>>>(x, E, out, cnt2, list2);
}